// Round 4
// baseline (158.252 us; speedup 1.0000x reference)
//
#include <hip/hip_runtime.h>

typedef __bf16 bf16_t;
typedef __bf16 bf16x4_t __attribute__((ext_vector_type(4)));
typedef __bf16 bf16x8 __attribute__((ext_vector_type(8)));
typedef float f32x4 __attribute__((ext_vector_type(4)));

#define NH 8
#define DH 32
#define QL 256
#define KL 256
#define CIN 64
#define HD 256  // NH*DH

__device__ __forceinline__ bf16_t f2bf(float x) { return (bf16_t)x; }

__device__ __forceinline__ f32x4 mfma16(bf16x8 a, bf16x8 b, f32x4 c) {
    return __builtin_amdgcn_mfma_f32_16x16x32_bf16(a, b, c, 0, 0, 0);
}

// ---------------------------------------------------------------------------
// pack_w: one-time repack of Wq/Wk/Wv/Wo into fragment-native bf16 layout.
// Frag elem j at lane(quad,l16):
//   WqF/WkF/WvF: W[ks*32+quad*8+j][h*32 + nt*16 + l16]   (B-operand, proj)
//   WoF:         Wo[h*32+quad*8+j][nt*16 + l16]          (B-operand, outproj)
__launch_bounds__(256)
__global__ void pack_w(const float* __restrict__ Wq, const float* __restrict__ Wk,
                       const float* __restrict__ Wv, const float* __restrict__ Wo,
                       bf16_t* __restrict__ WqF, bf16_t* __restrict__ WkF,
                       bf16_t* __restrict__ WvF, bf16_t* __restrict__ WoF) {
    const int h = blockIdx.x;
    const int tid = threadIdx.x, lane = tid & 63, w = tid >> 6;
    const int quad = lane >> 4, l16 = lane & 15;
    if (w < 3) {
        const float* __restrict__ W = (w == 0) ? Wq : (w == 1 ? Wk : Wv);
        bf16_t* __restrict__ F = (w == 0) ? WqF : (w == 1 ? WkF : WvF);
#pragma unroll
        for (int nt = 0; nt < 2; ++nt)
#pragma unroll
            for (int ks = 0; ks < 2; ++ks) {
                bf16x8 f;
#pragma unroll
                for (int j = 0; j < 8; ++j)
                    f[j] = f2bf(W[(ks * 32 + quad * 8 + j) * HD + h * DH + nt * 16 + l16]);
                *(bf16x8*)&F[(size_t)((h * 4 + nt * 2 + ks) * 512) + lane * 8] = f;
            }
    } else {
#pragma unroll
        for (int nt = 0; nt < 4; ++nt) {
            bf16x8 f;
#pragma unroll
            for (int j = 0; j < 8; ++j)
                f[j] = f2bf(Wo[(h * DH + quad * 8 + j) * CIN + nt * 16 + l16]);
            *(bf16x8*)&WoF[(size_t)((h * 4 + nt) * 512) + lane * 8] = f;
        }
    }
}

// ---------------------------------------------------------------------------
// fused_attn: one block = (s, 64-q-row quarter, 4-head group).
// r3 changes vs r2:
//  (1) rest=(qq,hg) in LOW 3 bits of blockIdx -> XCD = rest: each XCD's bias
//      slice is 4h x 64q x 256kv x 4B = 256 KB -> L2-RESIDENT (r2: s-fastest
//      made the slice 8 MB -> every bias read was L3; 256 MB/dispatch of L3
//      traffic was the stall budget).
//  (2) sK stored [256][32] with chunk-XOR swizzle (chunk ^= (row>>2)&3):
//      scalar C-stores spread quads across all 4 chunk slots (was a
//      structural 4-way conflict: 4.33M conflict-cycles/dispatch); b128
//      reads stay 16B-aligned, conflict-free. LDS 47.6 -> 42.6 KB.
__launch_bounds__(256, 3)
__global__ void fused_attn(const float* __restrict__ Xq, const float* __restrict__ Xkv,
                           const float* __restrict__ Mask, const float* __restrict__ Bias,
                           const bf16_t* __restrict__ WqF, const bf16_t* __restrict__ WkF,
                           const bf16_t* __restrict__ WvF, const bf16_t* __restrict__ WoF,
                           const float* __restrict__ Bo, float* __restrict__ Out) {
    const int b = blockIdx.x;
    const int rest = b & 7, s = b >> 3;   // rest fastest: XCD = rest -> bias L2-pins
    const int qq = rest & 3, hg = rest >> 2;
    const int tid = threadIdx.x, lane = tid & 63, w = tid >> 6;
    const int quad = lane >> 4, l16 = lane & 15;
    const int tg = qq * 4 + w;            // this wave's global q-tile (16 rows)
    const f32x4 vzero = {0.f, 0.f, 0.f, 0.f};

    __shared__ __attribute__((aligned(16))) bf16_t sK[KL * 32];    // 16.0 KB (swizzled)
    __shared__ __attribute__((aligned(16))) bf16_t sVT[DH][264];   // 16.5 KB
    __shared__ __attribute__((aligned(16))) bf16_t sB[4][16][72];  //  9.0 KB
    __shared__ __attribute__((aligned(16))) float sMask[KL];       //  1.0 KB

    // mask pre-combined: (m-1)*INF, shared by all heads/q of this s
    if (tid < 64) {
        const f32x4 m4 = *(const f32x4*)&Mask[s * KL + tid * 4];
        f32x4 mm;
#pragma unroll
        for (int j = 0; j < 4; ++j) mm[j] = (m4[j] - 1.0f) * 1.0e9f;
        *(f32x4*)&sMask[tid * 4] = mm;
    }

    // ---- X fragments, register-resident for all 4 heads of this group ----
    bf16x8 xk[4][2];  // Xkv A-frags: wave owns kv-tiles {4w..4w+3}
#pragma unroll
    for (int t = 0; t < 4; ++t) {
        const int row = (w * 4 + t) * 16 + l16;
        const float* src = &Xkv[(size_t)(s * QL + row) * CIN];
#pragma unroll
        for (int ks = 0; ks < 2; ++ks) {
            const f32x4 lo = *(const f32x4*)&src[ks * 32 + quad * 8];
            const f32x4 hi = *(const f32x4*)&src[ks * 32 + quad * 8 + 4];
            bf16x8 f;
#pragma unroll
            for (int j = 0; j < 4; ++j) { f[j] = f2bf(lo[j]); f[4 + j] = f2bf(hi[j]); }
            xk[t][ks] = f;
        }
    }
    bf16x8 xq[2];  // Xq A-frags for this wave's q-tile, pre-scaled 1/sqrt(32)
    {
        const int row = tg * 16 + l16;
        const float* src = &Xq[(size_t)(s * QL + row) * CIN];
#pragma unroll
        for (int ks = 0; ks < 2; ++ks) {
            const f32x4 lo = *(const f32x4*)&src[ks * 32 + quad * 8];
            const f32x4 hi = *(const f32x4*)&src[ks * 32 + quad * 8 + 4];
            bf16x8 f;
#pragma unroll
            for (int j = 0; j < 4; ++j) {
                f[j] = f2bf(lo[j] * 0.17677669529663687f);
                f[4 + j] = f2bf(hi[j] * 0.17677669529663687f);
            }
            xq[ks] = f;
        }
    }

    f32x4 acc[4];  // output accumulator: 16 q-rows x 64 out-cols (this head group)
#pragma unroll
    for (int nt = 0; nt < 4; ++nt) acc[nt] = vzero;

#pragma unroll 1
    for (int hh = 0; hh < 4; ++hh) {
        const int h = hg * 4 + hh;
        // -------------------- proj phase --------------------
        bf16x8 bk[2][2], bv[2][2];
#pragma unroll
        for (int nt = 0; nt < 2; ++nt)
#pragma unroll
            for (int ks = 0; ks < 2; ++ks) {
                bk[nt][ks] = *(const bf16x8*)&WkF[(size_t)((h * 4 + nt * 2 + ks) * 512) + lane * 8];
                bv[nt][ks] = *(const bf16x8*)&WvF[(size_t)((h * 4 + nt * 2 + ks) * 512) + lane * 8];
            }
        // K: C/D (row=quad*4+r, d=nt*16+l16) -> swizzled sK
        //   addr(row,col) = row*32 + ((col>>3 ^ (row>>2)&3)<<3) + (col&7)
        //   here (row>>2)&3 == quad, col>>3 == nt*2 + (l16>>3)
#pragma unroll
        for (int t = 0; t < 4; ++t) {
            const int r0 = (w * 4 + t) * 16 + quad * 4;
#pragma unroll
            for (int nt = 0; nt < 2; ++nt) {
                f32x4 c = mfma16(xk[t][0], bk[nt][0], vzero);
                c = mfma16(xk[t][1], bk[nt][1], c);
                const int chS = ((nt * 2 + (l16 >> 3)) ^ quad) << 3;
#pragma unroll
                for (int r = 0; r < 4; ++r)
                    sK[(r0 + r) * 32 + chS + (l16 & 7)] = f2bf(c[r]);
            }
        }
        // bias rides in early: 16 f32x4 from the XCD-pinned L2 slice;
        // latency hides under V/Q proj
        f32x4 sv[16];
        const float* bb = &Bias[(size_t)(h * QL + tg * 16 + l16) * KL];
#pragma unroll
        for (int ct = 0; ct < 16; ++ct) sv[ct] = *(const f32x4*)&bb[ct * 16 + quad * 4];
        // V: C/D rows are kv -> transpose-store to sVT[d][kv] as b64 packs
#pragma unroll
        for (int t = 0; t < 4; ++t) {
            const int c0 = (w * 4 + t) * 16 + quad * 4;
#pragma unroll
            for (int nt = 0; nt < 2; ++nt) {
                f32x4 c = mfma16(xk[t][0], bv[nt][0], vzero);
                c = mfma16(xk[t][1], bv[nt][1], c);
                bf16x4_t p;
#pragma unroll
                for (int r = 0; r < 4; ++r) p[r] = f2bf(c[r]);
                *(bf16x4_t*)&sVT[nt * 16 + l16][c0] = p;
            }
        }
        // Q: C/D -> per-wave bounce -> B-frag (same-wave DS order, no barrier)
        {
            bf16x8 bq[2][2];
#pragma unroll
            for (int nt = 0; nt < 2; ++nt)
#pragma unroll
                for (int ks = 0; ks < 2; ++ks)
                    bq[nt][ks] = *(const bf16x8*)&WqF[(size_t)((h * 4 + nt * 2 + ks) * 512) + lane * 8];
#pragma unroll
            for (int nt = 0; nt < 2; ++nt) {
                f32x4 c = mfma16(xq[0], bq[nt][0], vzero);
                c = mfma16(xq[1], bq[nt][1], c);
#pragma unroll
                for (int r = 0; r < 4; ++r) sB[w][quad * 4 + r][nt * 16 + l16] = f2bf(c[r]);
            }
        }
        const bf16x8 qfr = *(const bf16x8*)&sB[w][l16][quad * 8];

        __syncthreads();  // barrier 1: sK/sVT of head h visible

        // -------------------- attn phase --------------------
#pragma unroll
        for (int ct = 0; ct < 16; ++ct)
            sv[ct] += *(const f32x4*)&sMask[ct * 16 + quad * 4];  // broadcast read
        // S' = K·Q^T rides the C operand: C/D row=kv-local, col=q
        // swizzled A-frag read: row = ct*16+l16 -> (row>>2)&3 == (l16>>2)&3
#pragma unroll
        for (int ct = 0; ct < 16; ++ct) {
            const int row = ct * 16 + l16;
            const int chS = (quad ^ ((l16 >> 2) & 3)) << 3;
            const bf16x8 ak = *(const bf16x8*)&sK[row * 32 + chS];
            sv[ct] = mfma16(ak, qfr, sv[ct]);
        }
        // softmax over kv: tree-reduced (vector accumulators, 15/16-deep chains)
        f32x4 vmx = sv[0];
#pragma unroll
        for (int ct = 1; ct < 16; ++ct)
#pragma unroll
            for (int r = 0; r < 4; ++r) vmx[r] = fmaxf(vmx[r], sv[ct][r]);
        float mx = fmaxf(fmaxf(vmx[0], vmx[1]), fmaxf(vmx[2], vmx[3]));
        mx = fmaxf(mx, __shfl_xor(mx, 16, 64));
        mx = fmaxf(mx, __shfl_xor(mx, 32, 64));
        f32x4 vsum = vzero;
#pragma unroll
        for (int ct = 0; ct < 16; ++ct)
#pragma unroll
            for (int r = 0; r < 4; ++r) {
                const float e = __expf(sv[ct][r] - mx);
                sv[ct][r] = e;
                vsum[r] += e;
            }
        float sum = (vsum[0] + vsum[1]) + (vsum[2] + vsum[3]);
        sum += __shfl_xor(sum, 16, 64);
        sum += __shfl_xor(sum, 32, 64);
        const float rs = 1.0f / sum;

        // PV in four 64-kv chunks: P^T -> sB (64-col buffer) -> A-frags; V from sVT
        f32x4 o0 = vzero, o1 = vzero;
#pragma unroll
        for (int c = 0; c < 4; ++c) {
#pragma unroll
            for (int cc = 0; cc < 4; ++cc) {
                const int ct = c * 4 + cc;
                bf16x4_t pv;
#pragma unroll
                for (int r = 0; r < 4; ++r) pv[r] = f2bf(sv[ct][r] * rs);
                *(bf16x4_t*)&sB[w][l16][cc * 16 + quad * 4] = pv;
            }
#pragma unroll
            for (int ks = 0; ks < 2; ++ks) {
                const bf16x8 ap = *(const bf16x8*)&sB[w][l16][ks * 32 + quad * 8];
                const int cs = c * 2 + ks;
                const bf16x8 v0 = *(const bf16x8*)&sVT[l16][cs * 32 + quad * 8];
                const bf16x8 v1 = *(const bf16x8*)&sVT[16 + l16][cs * 32 + quad * 8];
                o0 = mfma16(ap, v0, o0);
                o1 = mfma16(ap, v1, o1);
            }
        }

        __syncthreads();  // barrier 2: sK/sVT free for head h+1

        // ---------- outproj accumulate (sB is per-wave: no extra barrier) ----------
        {
            bf16x8 bwo[4];
#pragma unroll
            for (int nt = 0; nt < 4; ++nt)
                bwo[nt] = *(const bf16x8*)&WoF[(size_t)((h * 4 + nt) * 512) + lane * 8];
#pragma unroll
            for (int r = 0; r < 4; ++r) {
                sB[w][quad * 4 + r][l16] = f2bf(o0[r]);
                sB[w][quad * 4 + r][16 + l16] = f2bf(o1[r]);
            }
            const bf16x8 af = *(const bf16x8*)&sB[w][l16][quad * 8];
#pragma unroll
            for (int nt = 0; nt < 4; ++nt) acc[nt] = mfma16(af, bwo[nt], acc[nt]);
        }
    }

    // ---------- epilogue: combine head-group partials via f32 atomics ----------
    const int orow = s * QL + tg * 16 + quad * 4;
#pragma unroll
    for (int nt = 0; nt < 4; ++nt) {
        const float bo = (hg == 0) ? Bo[nt * 16 + l16] : 0.0f;
#pragma unroll
        for (int r = 0; r < 4; ++r)
            atomicAdd(&Out[(size_t)(orow + r) * CIN + nt * 16 + l16], acc[nt][r] + bo);
    }
}

extern "C" void kernel_launch(void* const* d_in, const int* in_sizes, int n_in,
                              void* d_out, int out_size, void* d_ws, size_t ws_size,
                              hipStream_t stream) {
    const float* Xq   = (const float*)d_in[0];
    const float* Xkv  = (const float*)d_in[1];
    const float* Mask = (const float*)d_in[2];
    const float* Bias = (const float*)d_in[3];
    const float* Wq   = (const float*)d_in[4];
    const float* Wk   = (const float*)d_in[5];
    const float* Wv   = (const float*)d_in[6];
    const float* Wo   = (const float*)d_in[7];
    const float* Bo   = (const float*)d_in[8];
    float* Out = (float*)d_out;

    // 128 KB of fragment-native weights at the head of ws
    bf16_t* WqF = (bf16_t*)d_ws;
    bf16_t* WkF = WqF + 16384;
    bf16_t* WvF = WkF + 16384;
    bf16_t* WoF = WvF + 16384;

    pack_w<<<dim3(NH), 256, 0, stream>>>(Wq, Wk, Wv, Wo, WqF, WkF, WvF, WoF);
    hipMemsetAsync(d_out, 0, (size_t)out_size, stream);  // atomic-accumulate base
    fused_attn<<<dim3(1024), 256, 0, stream>>>(Xq, Xkv, Mask, Bias,
                                               WqF, WkF, WvF, WoF, Bo, Out);
}

// Round 5
// 131.023 us; speedup vs baseline: 1.2078x; 1.2078x over previous
//
#include <hip/hip_runtime.h>

typedef __bf16 bf16_t;
typedef __bf16 bf16x4_t __attribute__((ext_vector_type(4)));
typedef __bf16 bf16x8 __attribute__((ext_vector_type(8)));
typedef float f32x4 __attribute__((ext_vector_type(4)));

#define NH 8
#define DH 32
#define QL 256
#define KL 256
#define CIN 64
#define HD 256  // NH*DH

__device__ __forceinline__ bf16_t f2bf(float x) { return (bf16_t)x; }

__device__ __forceinline__ f32x4 mfma16(bf16x8 a, bf16x8 b, f32x4 c) {
    return __builtin_amdgcn_mfma_f32_16x16x32_bf16(a, b, c, 0, 0, 0);
}

// ---------------------------------------------------------------------------
// pack_w: one-time repack of Wq/Wk/Wv/Wo into fragment-native bf16 layout.
// Frag elem j at lane(quad,l16):
//   WqF/WkF/WvF: W[ks*32+quad*8+j][h*32 + nt*16 + l16]   (B-operand, proj)
//   WoF:         Wo[h*32+quad*8+j][nt*16 + l16]          (B-operand, outproj)
__launch_bounds__(256)
__global__ void pack_w(const float* __restrict__ Wq, const float* __restrict__ Wk,
                       const float* __restrict__ Wv, const float* __restrict__ Wo,
                       bf16_t* __restrict__ WqF, bf16_t* __restrict__ WkF,
                       bf16_t* __restrict__ WvF, bf16_t* __restrict__ WoF) {
    const int h = blockIdx.x;
    const int tid = threadIdx.x, lane = tid & 63, w = tid >> 6;
    const int quad = lane >> 4, l16 = lane & 15;
    if (w < 3) {
        const float* __restrict__ W = (w == 0) ? Wq : (w == 1 ? Wk : Wv);
        bf16_t* __restrict__ F = (w == 0) ? WqF : (w == 1 ? WkF : WvF);
#pragma unroll
        for (int nt = 0; nt < 2; ++nt)
#pragma unroll
            for (int ks = 0; ks < 2; ++ks) {
                bf16x8 f;
#pragma unroll
                for (int j = 0; j < 8; ++j)
                    f[j] = f2bf(W[(ks * 32 + quad * 8 + j) * HD + h * DH + nt * 16 + l16]);
                *(bf16x8*)&F[(size_t)((h * 4 + nt * 2 + ks) * 512) + lane * 8] = f;
            }
    } else {
#pragma unroll
        for (int nt = 0; nt < 4; ++nt) {
            bf16x8 f;
#pragma unroll
            for (int j = 0; j < 8; ++j)
                f[j] = f2bf(Wo[(h * DH + quad * 8 + j) * CIN + nt * 16 + l16]);
            *(bf16x8*)&WoF[(size_t)((h * 4 + nt) * 512) + lane * 8] = f;
        }
    }
}

// ---------------------------------------------------------------------------
// fused_pipe: one block = (s, 64-q-row quarter), 8 heads, software-pipelined.
// r5 structure (from r1/r2/r4 post-mortems: ordering/occupancy knobs neutral,
// phases latency-serial): double-buffered sK/sVT; phase h = attn(h) on buf p
// INTERLEAVED with proj(h+1) into buf 1-p and this head's bias loads; ONE
// barrier per head (9/block vs r1's 16). The ~36 independent proj MFMAs +
// LDS stores fill the QK-load / softmax / bias-latency bubbles.
//  - 512 blocks (s fastest -> XCD = s%8: Xkv/Out locality, r1-proven)
//  - sK: r4's harness-proven swizzled [256][32] (chunk ^= (row>>2)&3),
//    dbuf 32 KB; sVT [32][264] dbuf 33 KB; sB [4][16][72] 9 KB; mask 1 KB
//    -> 75 KB -> 2 blocks/CU.
//  - direct epilogue store (no atomics, no memset).
__launch_bounds__(256, 2)
__global__ void fused_pipe(const float* __restrict__ Xq, const float* __restrict__ Xkv,
                           const float* __restrict__ Mask, const float* __restrict__ Bias,
                           const bf16_t* __restrict__ WqF, const bf16_t* __restrict__ WkF,
                           const bf16_t* __restrict__ WvF, const bf16_t* __restrict__ WoF,
                           const float* __restrict__ Bo, float* __restrict__ Out) {
    const int b = blockIdx.x;
    const int s = b & 127, qq = b >> 7;   // s fastest: same-s blocks share an XCD
    const int tid = threadIdx.x, lane = tid & 63, w = tid >> 6;
    const int quad = lane >> 4, l16 = lane & 15;
    const int tg = qq * 4 + w;            // this wave's global q-tile (16 rows)
    const f32x4 vzero = {0.f, 0.f, 0.f, 0.f};

    __shared__ __attribute__((aligned(16))) bf16_t sK[2 * KL * 32];   // 32 KB dbuf, swizzled
    __shared__ __attribute__((aligned(16))) bf16_t sVT[2][DH][264];   // 33 KB dbuf
    __shared__ __attribute__((aligned(16))) bf16_t sB[4][16][72];     //  9 KB per-wave bounce
    __shared__ __attribute__((aligned(16))) float sMask[KL];          //  1 KB

    // mask pre-combined: (m-1)*INF, shared by all heads/q of this s
    if (tid < 64) {
        const f32x4 m4 = *(const f32x4*)&Mask[s * KL + tid * 4];
        f32x4 mm;
#pragma unroll
        for (int j = 0; j < 4; ++j) mm[j] = (m4[j] - 1.0f) * 1.0e9f;
        *(f32x4*)&sMask[tid * 4] = mm;
    }

    // ---- X fragments, register-resident for all 8 heads ----
    bf16x8 xk[4][2];  // Xkv A-frags: wave owns kv-tiles {4w..4w+3}
#pragma unroll
    for (int t = 0; t < 4; ++t) {
        const int row = (w * 4 + t) * 16 + l16;
        const float* src = &Xkv[(size_t)(s * QL + row) * CIN];
#pragma unroll
        for (int ks = 0; ks < 2; ++ks) {
            const f32x4 lo = *(const f32x4*)&src[ks * 32 + quad * 8];
            const f32x4 hi = *(const f32x4*)&src[ks * 32 + quad * 8 + 4];
            bf16x8 f;
#pragma unroll
            for (int j = 0; j < 4; ++j) { f[j] = f2bf(lo[j]); f[4 + j] = f2bf(hi[j]); }
            xk[t][ks] = f;
        }
    }
    bf16x8 xq[2];  // Xq A-frags for this wave's q-tile, pre-scaled 1/sqrt(32)
    {
        const int row = tg * 16 + l16;
        const float* src = &Xq[(size_t)(s * QL + row) * CIN];
#pragma unroll
        for (int ks = 0; ks < 2; ++ks) {
            const f32x4 lo = *(const f32x4*)&src[ks * 32 + quad * 8];
            const f32x4 hi = *(const f32x4*)&src[ks * 32 + quad * 8 + 4];
            bf16x8 f;
#pragma unroll
            for (int j = 0; j < 4; ++j) {
                f[j] = f2bf(lo[j] * 0.17677669529663687f);
                f[4 + j] = f2bf(hi[j] * 0.17677669529663687f);
            }
            xq[ks] = f;
        }
    }

    // K/V projection of head h into LDS buffer buf (indices: r4 harness-proven)
    auto projKV = [&](int h, int buf) {
        bf16x8 bk[2][2], bv[2][2];
#pragma unroll
        for (int nt = 0; nt < 2; ++nt)
#pragma unroll
            for (int ks = 0; ks < 2; ++ks) {
                bk[nt][ks] = *(const bf16x8*)&WkF[(size_t)((h * 4 + nt * 2 + ks) * 512) + lane * 8];
                bv[nt][ks] = *(const bf16x8*)&WvF[(size_t)((h * 4 + nt * 2 + ks) * 512) + lane * 8];
            }
        // K: C/D (row=quad*4+r, d=nt*16+l16) -> swizzled sK[buf]
#pragma unroll
        for (int t = 0; t < 4; ++t) {
            const int r0 = (w * 4 + t) * 16 + quad * 4;
#pragma unroll
            for (int nt = 0; nt < 2; ++nt) {
                f32x4 c = mfma16(xk[t][0], bk[nt][0], vzero);
                c = mfma16(xk[t][1], bk[nt][1], c);
                const int chS = ((nt * 2 + (l16 >> 3)) ^ quad) << 3;
#pragma unroll
                for (int r = 0; r < 4; ++r)
                    sK[buf * (KL * 32) + (r0 + r) * 32 + chS + (l16 & 7)] = f2bf(c[r]);
            }
        }
        // V: C/D rows are kv -> transpose-store to sVT[buf][d][kv] as b64 packs
#pragma unroll
        for (int t = 0; t < 4; ++t) {
            const int c0 = (w * 4 + t) * 16 + quad * 4;
#pragma unroll
            for (int nt = 0; nt < 2; ++nt) {
                f32x4 c = mfma16(xk[t][0], bv[nt][0], vzero);
                c = mfma16(xk[t][1], bv[nt][1], c);
                bf16x4_t p4;
#pragma unroll
                for (int r = 0; r < 4; ++r) p4[r] = f2bf(c[r]);
                *(bf16x4_t*)&sVT[buf][nt * 16 + l16][c0] = p4;
            }
        }
    };

    f32x4 acc[4];  // output accumulator: 16 q-rows x 64 out-cols
#pragma unroll
    for (int nt = 0; nt < 4; ++nt) acc[nt] = vzero;

    projKV(0, 0);       // prologue fills buf 0
    __syncthreads();    // buf0 + sMask visible

#pragma unroll 1
    for (int h = 0; h < NH; ++h) {
        const int p = h & 1;

        // ---- bias loads straight into sv (in flight across the whole phase) ----
        f32x4 sv[16];
        const float* bb = &Bias[(size_t)(h * QL + tg * 16 + l16) * KL];
#pragma unroll
        for (int ct = 0; ct < 16; ++ct) sv[ct] = *(const f32x4*)&bb[ct * 16 + quad * 4];

        // ---- Q-proj head h: C/D -> per-wave bounce -> B-frag (same-wave DS) ----
        bf16x8 qfr;
        {
            bf16x8 bq[2][2];
#pragma unroll
            for (int nt = 0; nt < 2; ++nt)
#pragma unroll
                for (int ks = 0; ks < 2; ++ks)
                    bq[nt][ks] = *(const bf16x8*)&WqF[(size_t)((h * 4 + nt * 2 + ks) * 512) + lane * 8];
#pragma unroll
            for (int nt = 0; nt < 2; ++nt) {
                f32x4 c = mfma16(xq[0], bq[nt][0], vzero);
                c = mfma16(xq[1], bq[nt][1], c);
#pragma unroll
                for (int r = 0; r < 4; ++r) sB[w][quad * 4 + r][nt * 16 + l16] = f2bf(c[r]);
            }
            qfr = *(const bf16x8*)&sB[w][l16][quad * 8];
        }

        // ---- Wo frags for this head's outproj (global, L2-hot; used at end) ----
        bf16x8 bwo[4];
#pragma unroll
        for (int nt = 0; nt < 4; ++nt)
            bwo[nt] = *(const bf16x8*)&WoF[(size_t)((h * 4 + nt) * 512) + lane * 8];

        // ---- proj(h+1) into buf 1-p: the independent work that fills this
        //      phase's QK-load / softmax / bias-latency bubbles ----
        if (h + 1 < NH) projKV(h + 1, p ^ 1);

        // ---- attn(h) on buf p ----
#pragma unroll
        for (int ct = 0; ct < 16; ++ct)
            sv[ct] += *(const f32x4*)&sMask[ct * 16 + quad * 4];  // broadcast read
        // S' = K·Q^T rides the C operand: C/D row=kv-local, col=q
#pragma unroll
        for (int ct = 0; ct < 16; ++ct) {
            const int row = ct * 16 + l16;
            const int chS = (quad ^ ((l16 >> 2) & 3)) << 3;
            const bf16x8 ak = *(const bf16x8*)&sK[p * (KL * 32) + row * 32 + chS];
            sv[ct] = mfma16(ak, qfr, sv[ct]);
        }
        // softmax over kv: tree-reduced
        f32x4 vmx = sv[0];
#pragma unroll
        for (int ct = 1; ct < 16; ++ct)
#pragma unroll
            for (int r = 0; r < 4; ++r) vmx[r] = fmaxf(vmx[r], sv[ct][r]);
        float mx = fmaxf(fmaxf(vmx[0], vmx[1]), fmaxf(vmx[2], vmx[3]));
        mx = fmaxf(mx, __shfl_xor(mx, 16, 64));
        mx = fmaxf(mx, __shfl_xor(mx, 32, 64));
        f32x4 vsum = vzero;
#pragma unroll
        for (int ct = 0; ct < 16; ++ct)
#pragma unroll
            for (int r = 0; r < 4; ++r) {
                const float e = __expf(sv[ct][r] - mx);
                sv[ct][r] = e;
                vsum[r] += e;
            }
        float sum = (vsum[0] + vsum[1]) + (vsum[2] + vsum[3]);
        sum += __shfl_xor(sum, 16, 64);
        sum += __shfl_xor(sum, 32, 64);
        const float rs = 1.0f / sum;

        // PV in four 64-kv chunks: P^T -> sB -> A-frags; V from sVT[p]
        f32x4 o0 = vzero, o1 = vzero;
#pragma unroll
        for (int c = 0; c < 4; ++c) {
#pragma unroll
            for (int cc = 0; cc < 4; ++cc) {
                const int ct = c * 4 + cc;
                bf16x4_t pv;
#pragma unroll
                for (int r = 0; r < 4; ++r) pv[r] = f2bf(sv[ct][r] * rs);
                *(bf16x4_t*)&sB[w][l16][cc * 16 + quad * 4] = pv;
            }
#pragma unroll
            for (int ks = 0; ks < 2; ++ks) {
                const bf16x8 ap = *(const bf16x8*)&sB[w][l16][ks * 32 + quad * 8];
                const int cs = c * 2 + ks;
                const bf16x8 v0 = *(const bf16x8*)&sVT[p][l16][cs * 32 + quad * 8];
                const bf16x8 v1 = *(const bf16x8*)&sVT[p][16 + l16][cs * 32 + quad * 8];
                o0 = mfma16(ap, v0, o0);
                o1 = mfma16(ap, v1, o1);
            }
        }

        // ---- outproj accumulate (sB per-wave, same-wave DS order) ----
        {
#pragma unroll
            for (int r = 0; r < 4; ++r) {
                sB[w][quad * 4 + r][l16] = f2bf(o0[r]);
                sB[w][quad * 4 + r][16 + l16] = f2bf(o1[r]);
            }
            const bf16x8 af = *(const bf16x8*)&sB[w][l16][quad * 8];
#pragma unroll
            for (int nt = 0; nt < 4; ++nt) acc[nt] = mfma16(af, bwo[nt], acc[nt]);
        }

        __syncthreads();  // single barrier/head: buf 1-p ready, buf p free
    }

    // -------------------- epilogue: direct store --------------------
    const int orow = s * QL + tg * 16 + quad * 4;
#pragma unroll
    for (int nt = 0; nt < 4; ++nt) {
        const float bo = Bo[nt * 16 + l16];
#pragma unroll
        for (int r = 0; r < 4; ++r)
            Out[(size_t)(orow + r) * CIN + nt * 16 + l16] = acc[nt][r] + bo;
    }
}

extern "C" void kernel_launch(void* const* d_in, const int* in_sizes, int n_in,
                              void* d_out, int out_size, void* d_ws, size_t ws_size,
                              hipStream_t stream) {
    const float* Xq   = (const float*)d_in[0];
    const float* Xkv  = (const float*)d_in[1];
    const float* Mask = (const float*)d_in[2];
    const float* Bias = (const float*)d_in[3];
    const float* Wq   = (const float*)d_in[4];
    const float* Wk   = (const float*)d_in[5];
    const float* Wv   = (const float*)d_in[6];
    const float* Wo   = (const float*)d_in[7];
    const float* Bo   = (const float*)d_in[8];
    float* Out = (float*)d_out;

    // 128 KB of fragment-native weights at the head of ws
    bf16_t* WqF = (bf16_t*)d_ws;
    bf16_t* WkF = WqF + 16384;
    bf16_t* WvF = WkF + 16384;
    bf16_t* WoF = WvF + 16384;

    pack_w<<<dim3(NH), 256, 0, stream>>>(Wq, Wk, Wv, Wo, WqF, WkF, WvF, WoF);
    fused_pipe<<<dim3(512), 256, 0, stream>>>(Xq, Xkv, Mask, Bias,
                                              WqF, WkF, WvF, WoF, Bo, Out);
}